// Round 3
// baseline (1035.892 us; speedup 1.0000x reference)
//
#include <hip/hip_runtime.h>
#include <hip/hip_fp16.h>
#include <math.h>

#define DFEAT 128
#define RSH 6          // log2(range size)
#define RSZ 64         // nodes per range
#define BINT 512       // threads per bin/scatter block
#define EPB 4096       // edges per bin/scatter block (8 per thread)
#define MAXNR 1024     // max ranges supported (N <= 65536)
typedef unsigned long long u64;
typedef unsigned int u32;
typedef unsigned short u16;
#define ENDK 0xFFFFFFFFFFFFFFFFULL

// ---------------- primary path: atomic-free coarse counting sort ----------------

// A: blocks [0, EB): LDS histogram of dst>>RSH over this block's 4096 edges,
//    written coalesced to ghist[range][block]. blocks [EB, ..): elu -> emb2 fp16.
__global__ __launch_bounds__(512) void hist_elu_kernel(
        const float* __restrict__ x, const float* __restrict__ w,
        __half* __restrict__ emb2, int total4,
        const int* __restrict__ dst, int E,
        u32* __restrict__ ghist, int EB, int NR) {
    if ((int)blockIdx.x < EB) {
        __shared__ u32 hist[MAXNR];
        int tid = threadIdx.x;
        for (int i = tid; i < NR; i += BINT) hist[i] = 0;
        __syncthreads();
        int base = blockIdx.x * EPB;
#pragma unroll 8
        for (int i = 0; i < 8; ++i) {
            int e = base + tid + i * BINT;
            if (e < E) atomicAdd(&hist[((u32)dst[e]) >> RSH], 1u);
        }
        __syncthreads();
        for (int r = tid; r < NR; r += BINT)
            ghist[(size_t)r * EB + blockIdx.x] = hist[r];
    } else {
        int idx = (blockIdx.x - EB) * BINT + threadIdx.x;
        if (idx >= total4) return;
        float4 xv = ((const float4*)x)[idx];
        float4 wv = ((const float4*)w)[idx & (DFEAT / 4 - 1)];
        float a, r0, r1, r2, r3;
        a = xv.x * wv.x; r0 = 2.0f * (a > 0.0f ? a : (__expf(a) - 1.0f));
        a = xv.y * wv.y; r1 = 2.0f * (a > 0.0f ? a : (__expf(a) - 1.0f));
        a = xv.z * wv.z; r2 = 2.0f * (a > 0.0f ? a : (__expf(a) - 1.0f));
        a = xv.w * wv.w; r3 = 2.0f * (a > 0.0f ? a : (__expf(a) - 1.0f));
        __half2 h01 = __floats2half2_rn(r0, r1);
        __half2 h23 = __floats2half2_rn(r2, r3);
        uint2 pk;
        pk.x = *(u32*)&h01;
        pk.y = *(u32*)&h23;
        ((uint2*)emb2)[idx] = pk;
    }
}

// Exclusive scan in place over g[0..M), single block of 1024 threads.
__global__ __launch_bounds__(1024) void scan_kernel(u32* __restrict__ g, int M) {
    __shared__ u32 part[1024];
    int t = threadIdx.x;
    int K = (M + 1023) >> 10;
    int lo = t * K;
    int hi = lo + K; if (hi > M) hi = M;
    u32 s = 0;
    for (int i = lo; i < hi; ++i) s += g[i];
    part[t] = s;
    __syncthreads();
    // Kogge-Stone inclusive scan of partials
    for (int d = 1; d < 1024; d <<= 1) {
        u32 v = (t >= d) ? part[t - d] : 0u;
        __syncthreads();
        part[t] += v;
        __syncthreads();
    }
    u32 p = (t == 0) ? 0u : part[t - 1];
    for (int i = lo; i < hi; ++i) {
        u32 v = g[i];
        g[i] = p;
        p += v;
    }
}

// B: re-read edges; claim positions via LDS atomics only; write (dl<<16|src)
// pairs into per-(range,block) contiguous runs (sequential-pointer writes).
__global__ __launch_bounds__(512) void scatter_pairs_kernel(
        const int* __restrict__ src, const int* __restrict__ dst, int E,
        const u32* __restrict__ ghist, int EB, int NR,
        u32* __restrict__ pairs) {
    __shared__ u32 off[MAXNR];
    int tid = threadIdx.x;
    for (int r = tid; r < NR; r += BINT)
        off[r] = ghist[(size_t)r * EB + blockIdx.x];
    __syncthreads();
    int base = blockIdx.x * EPB;
#pragma unroll 8
    for (int i = 0; i < 8; ++i) {
        int e = base + tid + i * BINT;
        if (e < E) {
            u32 d = (u32)dst[e];
            u32 s = (u32)src[e];
            u32 r = d >> RSH;
            u32 p = atomicAdd(&off[r], 1u);
            pairs[p] = ((d & (RSZ - 1)) << 16) | s;
        }
    }
}

// C: one block per 64-node range. fp32 LDS accumulator, two planes (x/y) so
// ds_add_f32 is 2-lanes/bank (free). Reads contiguous pair segment; gathers
// emb2 rows (64 lanes x 4B = one 256B row); coalesced float2 writeout.
__global__ __launch_bounds__(512) void gather_range_kernel(
        const __half* __restrict__ emb2, const u32* __restrict__ pairs,
        const u32* __restrict__ ghist, int EB, int NR, int E,
        float* __restrict__ out, int N) {
    __shared__ float accX[RSZ * 64];
    __shared__ float accY[RSZ * 64];
    int r = blockIdx.x;
    int tid = threadIdx.x;
    for (int i = tid; i < RSZ * 64; i += BINT) { accX[i] = 0.0f; accY[i] = 0.0f; }
    u32 s0 = ghist[(size_t)r * EB];
    u32 s1 = (r + 1 < NR) ? ghist[(size_t)(r + 1) * EB] : (u32)E;
    __syncthreads();
    int lane = tid & 63;
    int wave = tid >> 6;
    int cnt = (int)(s1 - s0);
    for (int base = wave * 64; base < cnt; base += 8 * 64) {
        int m = cnt - base; if (m > 64) m = 64;
        u32 pr = 0;
        if (lane < m) pr = pairs[s0 + base + lane];
        int jj = 0;
        for (; jj + 4 <= m; jj += 4) {
            u32 p0 = (u32)__shfl((int)pr, jj);
            u32 p1 = (u32)__shfl((int)pr, jj + 1);
            u32 p2 = (u32)__shfl((int)pr, jj + 2);
            u32 p3 = (u32)__shfl((int)pr, jj + 3);
            u32 h0 = ((const u32*)(emb2 + (size_t)(p0 & 0xFFFF) * DFEAT))[lane];
            u32 h1 = ((const u32*)(emb2 + (size_t)(p1 & 0xFFFF) * DFEAT))[lane];
            u32 h2 = ((const u32*)(emb2 + (size_t)(p2 & 0xFFFF) * DFEAT))[lane];
            u32 h3 = ((const u32*)(emb2 + (size_t)(p3 & 0xFFFF) * DFEAT))[lane];
            float2 f0 = __half22float2(*(__half2*)&h0);
            float2 f1 = __half22float2(*(__half2*)&h1);
            float2 f2 = __half22float2(*(__half2*)&h2);
            float2 f3 = __half22float2(*(__half2*)&h3);
            atomicAdd(&accX[(p0 >> 16) * 64 + lane], f0.x);
            atomicAdd(&accY[(p0 >> 16) * 64 + lane], f0.y);
            atomicAdd(&accX[(p1 >> 16) * 64 + lane], f1.x);
            atomicAdd(&accY[(p1 >> 16) * 64 + lane], f1.y);
            atomicAdd(&accX[(p2 >> 16) * 64 + lane], f2.x);
            atomicAdd(&accY[(p2 >> 16) * 64 + lane], f2.y);
            atomicAdd(&accX[(p3 >> 16) * 64 + lane], f3.x);
            atomicAdd(&accY[(p3 >> 16) * 64 + lane], f3.y);
        }
        for (; jj < m; ++jj) {
            u32 p0 = (u32)__shfl((int)pr, jj);
            u32 h0 = ((const u32*)(emb2 + (size_t)(p0 & 0xFFFF) * DFEAT))[lane];
            float2 f0 = __half22float2(*(__half2*)&h0);
            atomicAdd(&accX[(p0 >> 16) * 64 + lane], f0.x);
            atomicAdd(&accY[(p0 >> 16) * 64 + lane], f0.y);
        }
    }
    __syncthreads();
    int rows_lo = r << RSH;
    for (int i = tid; i < RSZ * 64; i += BINT) {
        int row = i >> 6;
        int col = i & 63;
        int n = rows_lo + row;
        if (n < N)
            ((float2*)out)[(size_t)n * 64 + col] =
                make_float2(accX[row * 64 + col], accY[row * 64 + col]);
    }
}

// ---------------- fallback paths ----------------

__global__ void bin_elu_ll_kernel(const float* __restrict__ x,
                                  const float* __restrict__ w,
                                  __half* __restrict__ emb2, int total4,
                                  const int* __restrict__ src,
                                  const int* __restrict__ dst, int E,
                                  u64* __restrict__ head,
                                  u64* __restrict__ nxt,
                                  int binBlocks) {
    if ((int)blockIdx.x < binBlocks) {
        int base = blockIdx.x * 1024 + threadIdx.x;
        for (int q = 0; q < 4; ++q) {
            int e = base + q * 256;
            if (e < E) {
                int s = src[e];
                int d = dst[e];
                u64 old = atomicExch(&head[d], ((u64)(u32)s << 32) | (u32)e);
                nxt[e] = old;
            }
        }
    } else {
        int idx = (blockIdx.x - binBlocks) * blockDim.x + threadIdx.x;
        if (idx >= total4) return;
        float4 xv = ((const float4*)x)[idx];
        float4 wv = ((const float4*)w)[idx & (DFEAT / 4 - 1)];
        float a, r0, r1, r2, r3;
        a = xv.x * wv.x; r0 = 2.0f * (a > 0.0f ? a : (__expf(a) - 1.0f));
        a = xv.y * wv.y; r1 = 2.0f * (a > 0.0f ? a : (__expf(a) - 1.0f));
        a = xv.z * wv.z; r2 = 2.0f * (a > 0.0f ? a : (__expf(a) - 1.0f));
        a = xv.w * wv.w; r3 = 2.0f * (a > 0.0f ? a : (__expf(a) - 1.0f));
        __half2 h01 = __floats2half2_rn(r0, r1);
        __half2 h23 = __floats2half2_rn(r2, r3);
        uint2 pk;
        pk.x = *(u32*)&h01;
        pk.y = *(u32*)&h23;
        ((uint2*)emb2)[idx] = pk;
    }
}

__global__ void gather_ll_kernel(const __half* __restrict__ emb2,
                                 const u64* __restrict__ head,
                                 const u64* __restrict__ nxt,
                                 float* __restrict__ out, int N) {
    int wid = (blockIdx.x * blockDim.x + threadIdx.x) >> 6;
    int lane = threadIdx.x & 63;
    int nA = wid * 2;
    int nB = nA + 1;
    if (nA >= N) return;
    bool hasB = (nB < N);
    u64 curA = head[nA];
    u64 curB = hasB ? head[nB] : ENDK;
    float2 accA = make_float2(0.0f, 0.0f);
    float2 accB = make_float2(0.0f, 0.0f);
    while (curA != ENDK || curB != ENDK) {
        bool aA = (curA != ENDK);
        bool aB = (curB != ENDK);
        u64 cA = curA, cB = curB;
        u32 uA = 0, uB = 0;
        if (aA) uA = ((const u32*)(emb2 + ((size_t)(cA >> 32)) * DFEAT))[lane];
        if (aB) uB = ((const u32*)(emb2 + ((size_t)(cB >> 32)) * DFEAT))[lane];
        if (aA) curA = nxt[(u32)cA];
        if (aB) curB = nxt[(u32)cB];
        if (aA) {
            float2 f = __half22float2(*(__half2*)&uA);
            accA.x += f.x; accA.y += f.y;
        }
        if (aB) {
            float2 f = __half22float2(*(__half2*)&uB);
            accB.x += f.x; accB.y += f.y;
        }
    }
    ((float2*)(out + (size_t)nA * DFEAT))[lane] = accA;
    if (hasB) ((float2*)(out + (size_t)nB * DFEAT))[lane] = accB;
}

__global__ void scatter_fused_kernel(const float* __restrict__ x,
                                     const float* __restrict__ w,
                                     const int* __restrict__ src,
                                     const int* __restrict__ dst,
                                     float* __restrict__ out, int E) {
    int t = blockIdx.x * blockDim.x + threadIdx.x;
    int edge = t >> 5;
    int lane = t & 31;
    if (edge >= E) return;
    int s = src[edge];
    int d = dst[edge];
    float4 xv = ((const float4*)(x + (size_t)s * DFEAT))[lane];
    float4 wv = ((const float4*)w)[lane];
    float4 v;
    float a;
    a = xv.x * wv.x; v.x = 2.0f * (a > 0.0f ? a : (__expf(a) - 1.0f));
    a = xv.y * wv.y; v.y = 2.0f * (a > 0.0f ? a : (__expf(a) - 1.0f));
    a = xv.z * wv.z; v.z = 2.0f * (a > 0.0f ? a : (__expf(a) - 1.0f));
    a = xv.w * wv.w; v.w = 2.0f * (a > 0.0f ? a : (__expf(a) - 1.0f));
    float* op = out + (size_t)d * DFEAT + lane * 4;
    unsafeAtomicAdd(op + 0, v.x);
    unsafeAtomicAdd(op + 1, v.y);
    unsafeAtomicAdd(op + 2, v.z);
    unsafeAtomicAdd(op + 3, v.w);
}

extern "C" void kernel_launch(void* const* d_in, const int* in_sizes, int n_in,
                              void* d_out, int out_size, void* d_ws, size_t ws_size,
                              hipStream_t stream) {
    const float* x   = (const float*)d_in[0];   // graph_embedding [N, 128]
    const float* w   = (const float*)d_in[1];   // weight [1, 128]
    const int*   src = (const int*)d_in[3];     // src [E]
    const int*   dst = (const int*)d_in[4];     // dst [E]
    float* out = (float*)d_out;

    const int ND = in_sizes[0];          // N * 128
    const int N  = ND / DFEAT;           // 50000
    const int E  = in_sizes[2];          // 800000

    const int EB = (E + EPB - 1) / EPB;                 // 196 bin/scatter blocks
    const int NR = (N + RSZ - 1) >> RSH;                // 782 ranges

    size_t emb_bytes   = ((size_t)ND * sizeof(__half) + 15) & ~(size_t)15;        // 12.8 MB
    size_t ghist_bytes = ((size_t)NR * EB * sizeof(u32) + 15) & ~(size_t)15;      // ~0.6 MB
    size_t pairs_bytes = ((size_t)E * sizeof(u32) + 15) & ~(size_t)15;            // 3.2 MB
    size_t total_new = emb_bytes + ghist_bytes + pairs_bytes;                     // ~16.6 MB

    size_t head64_bytes = ((size_t)N * sizeof(u64) + 15) & ~(size_t)15;
    size_t nxt64_bytes  = ((size_t)E * sizeof(u64) + 15) & ~(size_t)15;
    size_t total_old = emb_bytes + head64_bytes + nxt64_bytes;                    // 19.6 MB

    int total4 = ND / 4;

    if (ws_size >= total_new && N <= 65536) {   // src fits u16, NR <= MAXNR
        char* p = (char*)d_ws;
        __half* emb2  = (__half*)p;  p += emb_bytes;
        u32*    ghist = (u32*)p;     p += ghist_bytes;
        u32*    pairs = (u32*)p;

        int eluBlocks = (total4 + BINT - 1) / BINT;
        hist_elu_kernel<<<EB + eluBlocks, BINT, 0, stream>>>(
            x, w, emb2, total4, dst, E, ghist, EB, NR);

        scan_kernel<<<1, 1024, 0, stream>>>(ghist, NR * EB);

        scatter_pairs_kernel<<<EB, BINT, 0, stream>>>(src, dst, E, ghist, EB, NR, pairs);

        gather_range_kernel<<<NR, BINT, 0, stream>>>(
            emb2, pairs, ghist, EB, NR, E, out, N);
    } else if (ws_size >= total_old) {
        char* p = (char*)d_ws;
        __half* emb2 = (__half*)p;  p += emb_bytes;
        u64*    head = (u64*)p;     p += head64_bytes;
        u64*    nxt  = (u64*)p;

        hipMemsetAsync(head, 0xFF, (size_t)N * sizeof(u64), stream);

        int eluBlocks256 = (total4 + 255) / 256;
        int binBlocks = (E + 1023) / 1024;
        bin_elu_ll_kernel<<<binBlocks + eluBlocks256, 256, 0, stream>>>(
            x, w, emb2, total4, src, dst, E, head, nxt, binBlocks);

        long long waves = (N + 1) / 2;
        long long thr = waves * 64;
        gather_ll_kernel<<<(int)((thr + 255) / 256), 256, 0, stream>>>(
            emb2, head, nxt, out, N);
    } else {
        hipMemsetAsync(d_out, 0, (size_t)out_size * sizeof(float), stream);
        long long threads = (long long)E * 32;
        scatter_fused_kernel<<<(int)((threads + 255) / 256), 256, 0, stream>>>(x, w, src, dst, out, E);
    }
}

// Round 4
// 328.331 us; speedup vs baseline: 3.1550x; 3.1550x over previous
//
#include <hip/hip_runtime.h>
#include <hip/hip_fp16.h>
#include <math.h>

#define DFEAT 128
#define RSH 6            // log2(rows per range)
#define RSZ 64           // rows per range
#define NT  512          // threads per block
#define NB  512          // blocks in persistent grid (2 per CU, guaranteed resident)
#define EPB 4096         // edges per hist/scatter chunk
#define EPQ (EPB / NT)   // 8 edges per thread per chunk
#define CHUNK 2048       // pairs per sort chunk in gather
#define MAXNR 1024
#define TILESH 9         // scan tile = 512 elements (== NT)
#define TILE (1 << TILESH)
typedef unsigned long long u64;
typedef unsigned int u32;
typedef unsigned short u16;
#define ENDK 0xFFFFFFFFFFFFFFFFULL

// Device-scope monotonic spin barrier. Safe because all NB blocks are
// co-resident (NB = 2 blocks/CU * 256 CU, enforced by __launch_bounds__).
__device__ __forceinline__ void grid_barrier(u32* bar, u32 target) {
    __syncthreads();
    if (threadIdx.x == 0) {
        __threadfence();                       // release
        atomicAdd(bar, 1u);
        while (__hip_atomic_load(bar, __ATOMIC_RELAXED, __HIP_MEMORY_SCOPE_AGENT) < target)
            __builtin_amdgcn_s_sleep(8);
        __threadfence();                       // acquire
    }
    __syncthreads();
}

__device__ __forceinline__ void elu_store(const float* x, const float* w,
                                          __half* emb2, int i) {
    float4 xv = ((const float4*)x)[i];
    float4 wv = ((const float4*)w)[i & (DFEAT / 4 - 1)];
    float a, r0, r1, r2, r3;
    a = xv.x * wv.x; r0 = 2.0f * (a > 0.0f ? a : (__expf(a) - 1.0f));
    a = xv.y * wv.y; r1 = 2.0f * (a > 0.0f ? a : (__expf(a) - 1.0f));
    a = xv.z * wv.z; r2 = 2.0f * (a > 0.0f ? a : (__expf(a) - 1.0f));
    a = xv.w * wv.w; r3 = 2.0f * (a > 0.0f ? a : (__expf(a) - 1.0f));
    __half2 h01 = __floats2half2_rn(r0, r1);
    __half2 h23 = __floats2half2_rn(r2, r3);
    uint2 pk;
    pk.x = *(u32*)&h01;
    pk.y = *(u32*)&h23;
    ((uint2*)emb2)[i] = pk;
}

__global__ __launch_bounds__(NT, 4) void mono_kernel(
        const float* __restrict__ x, const float* __restrict__ w,
        const int* __restrict__ src, const int* __restrict__ dst,
        __half* __restrict__ emb2, u32* __restrict__ ghist,
        u32* __restrict__ tsum, u32* __restrict__ pairs,
        u32* __restrict__ bar, float* __restrict__ out,
        int total4, int E, int N, int EB, int NR, int M) {
    __shared__ __align__(16) char shraw[5248];
    __shared__ u32 cur_r;
    const int b = blockIdx.x;
    const int tid = threadIdx.x;
    u32* wrk = bar + 1;

    // ---- P1: per-chunk LDS histogram of dst>>RSH (+ elu grid-strided) ----
    {
        u32* hist = (u32*)shraw;
        for (int c = b; c < EB; c += NB) {
            for (int i = tid; i < NR; i += NT) hist[i] = 0;
            __syncthreads();
            int base = c * EPB;
#pragma unroll
            for (int q = 0; q < EPQ; ++q) {
                int e = base + tid + q * NT;
                if (e < E) atomicAdd(&hist[((u32)dst[e]) >> RSH], 1u);
            }
            __syncthreads();
            for (int r = tid; r < NR; r += NT)
                ghist[(size_t)r * EB + c] = hist[r];
            __syncthreads();
        }
        for (int i = b * NT + tid; i < total4; i += NB * NT)
            elu_store(x, w, emb2, i);
    }
    grid_barrier(bar, NB);

    // ---- P2a: per-block tile scan (tile = 512, coalesced) ----
    {
        u32* sc = (u32*)shraw;
        int i = (b << TILESH) + tid;
        u32 v = (i < M) ? ghist[i] : 0u;
        sc[tid] = v;
        __syncthreads();
        for (int d = 1; d < NT; d <<= 1) {
            u32 o = (tid >= d) ? sc[tid - d] : 0u;
            __syncthreads();
            sc[tid] += o;
            __syncthreads();
        }
        u32 incl = sc[tid];
        u32 tot = sc[NT - 1];
        if (i < M) ghist[i] = incl - v;       // local-exclusive
        if (tid == 0) tsum[b] = tot;
    }
    grid_barrier(bar, 2 * NB);

    // ---- P2b: block 0 scans the NB tile sums (exclusive) ----
    if (b == 0) {
        u32* sc = (u32*)shraw;
        u32 v = tsum[tid];
        sc[tid] = v;
        __syncthreads();
        for (int d = 1; d < NT; d <<= 1) {
            u32 o = (tid >= d) ? sc[tid - d] : 0u;
            __syncthreads();
            sc[tid] += o;
            __syncthreads();
        }
        tsum[tid] = sc[tid] - v;
    }
    grid_barrier(bar, 3 * NB);

    // ---- P3: scatter pairs into per-(range,chunk) contiguous runs ----
    {
        u32* off = (u32*)shraw;
        for (int c = b; c < EB; c += NB) {
            for (int r = tid; r < NR; r += NT) {
                u32 idx = (u32)r * EB + (u32)c;
                off[r] = ghist[idx] + tsum[idx >> TILESH];
            }
            __syncthreads();
            int base = c * EPB;
#pragma unroll
            for (int q = 0; q < EPQ; ++q) {
                int e = base + tid + q * NT;
                if (e < E) {
                    u32 d = (u32)dst[e];
                    u32 s = (u32)src[e];
                    u32 p = atomicAdd(&off[d >> RSH], 1u);
                    pairs[p] = ((d & (RSZ - 1)) << 16) | s;
                }
            }
            __syncthreads();
        }
    }
    grid_barrier(bar, 4 * NB);

    // ---- P4: per-range LDS counting-sort by row, register-accum gather ----
    {
        u16* sorted = (u16*)shraw;                       // 4096 B
        u32* bcnt   = (u32*)(shraw + 2 * CHUNK);         // 65 * 4
        u32* bstart = (u32*)(shraw + 2 * CHUNK + 272);   // 65 * 4
        const int wv = tid >> 6;
        const int lane = tid & 63;
        while (true) {
            if (tid == 0) cur_r = atomicAdd(wrk, 1u);
            __syncthreads();
            int r = (int)cur_r;
            if (r >= NR) break;
            u32 idx0 = (u32)r * EB;
            u32 s0 = ghist[idx0] + tsum[idx0 >> TILESH];
            u32 idx1 = idx0 + (u32)EB;
            u32 s1 = (r + 1 < NR) ? (ghist[idx1] + tsum[idx1 >> TILESH]) : (u32)E;
            float2 av[8];
#pragma unroll
            for (int rr = 0; rr < 8; ++rr) av[rr] = make_float2(0.0f, 0.0f);
            for (u32 pos = s0; pos < s1; pos += CHUNK) {
                int csz = (int)((s1 - pos < (u32)CHUNK) ? (s1 - pos) : (u32)CHUNK);
                if (tid < RSZ + 1) bcnt[tid] = 0;
                __syncthreads();
                u32 pr[4]; int rw[4];
#pragma unroll
                for (int q = 0; q < 4; ++q) {
                    int i = tid + q * NT;
                    rw[q] = -1; pr[q] = 0;
                    if (i < csz) {
                        pr[q] = pairs[pos + i];
                        rw[q] = (int)(pr[q] >> 16);
                        atomicAdd(&bcnt[rw[q]], 1u);
                    }
                }
                __syncthreads();
                if (tid < RSZ) {
                    u32 vv = bcnt[tid];
                    u32 inc = vv;
#pragma unroll
                    for (int d = 1; d < RSZ; d <<= 1) {
                        u32 o = __shfl_up(inc, d);
                        if (lane >= d) inc += o;
                    }
                    bstart[tid] = inc - vv;
                    bcnt[tid]   = inc - vv;
                    if (tid == RSZ - 1) bstart[RSZ] = inc;
                }
                __syncthreads();
#pragma unroll
                for (int q = 0; q < 4; ++q) {
                    if (rw[q] >= 0) {
                        u32 p = atomicAdd(&bcnt[rw[q]], 1u);
                        sorted[p] = (u16)(pr[q] & 0xFFFFu);
                    }
                }
                __syncthreads();
                // wave wv owns rows [wv*8, wv*8+8); register accumulation,
                // up to 8 independent 256B row loads in flight.
#pragma unroll
                for (int rr = 0; rr < 8; ++rr) {
                    int row = wv * 8 + rr;
                    int jb = (int)bstart[row], je = (int)bstart[row + 1];
                    for (int j = jb; j < je; j += 8) {
                        int ml = je - j; if (ml > 8) ml = 8;
                        u32 hh[8];
#pragma unroll
                        for (int i2 = 0; i2 < 8; ++i2)
                            if (i2 < ml) {
                                u32 ssrc = (u32)sorted[j + i2];
                                hh[i2] = ((const u32*)(emb2 + (size_t)ssrc * DFEAT))[lane];
                            }
#pragma unroll
                        for (int i2 = 0; i2 < 8; ++i2)
                            if (i2 < ml) {
                                float2 f = __half22float2(*(__half2*)&hh[i2]);
                                av[rr].x += f.x; av[rr].y += f.y;
                            }
                    }
                }
                __syncthreads();
            }
#pragma unroll
            for (int rr = 0; rr < 8; ++rr) {
                int n = (r << RSH) + wv * 8 + rr;
                if (n < N)
                    ((float2*)out)[(size_t)n * (DFEAT / 2) + lane] = av[rr];
            }
        }
    }
}

// ---------------- fallback paths (unchanged) ----------------

__global__ void bin_elu_ll_kernel(const float* __restrict__ x,
                                  const float* __restrict__ w,
                                  __half* __restrict__ emb2, int total4,
                                  const int* __restrict__ src,
                                  const int* __restrict__ dst, int E,
                                  u64* __restrict__ head,
                                  u64* __restrict__ nxt,
                                  int binBlocks) {
    if ((int)blockIdx.x < binBlocks) {
        int base = blockIdx.x * 1024 + threadIdx.x;
        for (int q = 0; q < 4; ++q) {
            int e = base + q * 256;
            if (e < E) {
                int s = src[e];
                int d = dst[e];
                u64 old = atomicExch(&head[d], ((u64)(u32)s << 32) | (u32)e);
                nxt[e] = old;
            }
        }
    } else {
        int idx = (blockIdx.x - binBlocks) * blockDim.x + threadIdx.x;
        if (idx >= total4) return;
        elu_store(x, w, emb2, idx);
    }
}

__global__ void gather_ll_kernel(const __half* __restrict__ emb2,
                                 const u64* __restrict__ head,
                                 const u64* __restrict__ nxt,
                                 float* __restrict__ out, int N) {
    int wid = (blockIdx.x * blockDim.x + threadIdx.x) >> 6;
    int lane = threadIdx.x & 63;
    int nA = wid * 2;
    int nB = nA + 1;
    if (nA >= N) return;
    bool hasB = (nB < N);
    u64 curA = head[nA];
    u64 curB = hasB ? head[nB] : ENDK;
    float2 accA = make_float2(0.0f, 0.0f);
    float2 accB = make_float2(0.0f, 0.0f);
    while (curA != ENDK || curB != ENDK) {
        bool aA = (curA != ENDK);
        bool aB = (curB != ENDK);
        u64 cA = curA, cB = curB;
        u32 uA = 0, uB = 0;
        if (aA) uA = ((const u32*)(emb2 + ((size_t)(cA >> 32)) * DFEAT))[lane];
        if (aB) uB = ((const u32*)(emb2 + ((size_t)(cB >> 32)) * DFEAT))[lane];
        if (aA) curA = nxt[(u32)cA];
        if (aB) curB = nxt[(u32)cB];
        if (aA) {
            float2 f = __half22float2(*(__half2*)&uA);
            accA.x += f.x; accA.y += f.y;
        }
        if (aB) {
            float2 f = __half22float2(*(__half2*)&uB);
            accB.x += f.x; accB.y += f.y;
        }
    }
    ((float2*)(out + (size_t)nA * DFEAT))[lane] = accA;
    if (hasB) ((float2*)(out + (size_t)nB * DFEAT))[lane] = accB;
}

__global__ void scatter_fused_kernel(const float* __restrict__ x,
                                     const float* __restrict__ w,
                                     const int* __restrict__ src,
                                     const int* __restrict__ dst,
                                     float* __restrict__ out, int E) {
    int t = blockIdx.x * blockDim.x + threadIdx.x;
    int edge = t >> 5;
    int lane = t & 31;
    if (edge >= E) return;
    int s = src[edge];
    int d = dst[edge];
    float4 xv = ((const float4*)(x + (size_t)s * DFEAT))[lane];
    float4 wv = ((const float4*)w)[lane];
    float4 v;
    float a;
    a = xv.x * wv.x; v.x = 2.0f * (a > 0.0f ? a : (__expf(a) - 1.0f));
    a = xv.y * wv.y; v.y = 2.0f * (a > 0.0f ? a : (__expf(a) - 1.0f));
    a = xv.z * wv.z; v.z = 2.0f * (a > 0.0f ? a : (__expf(a) - 1.0f));
    a = xv.w * wv.w; v.w = 2.0f * (a > 0.0f ? a : (__expf(a) - 1.0f));
    float* op = out + (size_t)d * DFEAT + lane * 4;
    unsafeAtomicAdd(op + 0, v.x);
    unsafeAtomicAdd(op + 1, v.y);
    unsafeAtomicAdd(op + 2, v.z);
    unsafeAtomicAdd(op + 3, v.w);
}

extern "C" void kernel_launch(void* const* d_in, const int* in_sizes, int n_in,
                              void* d_out, int out_size, void* d_ws, size_t ws_size,
                              hipStream_t stream) {
    const float* x   = (const float*)d_in[0];   // graph_embedding [N, 128]
    const float* w   = (const float*)d_in[1];   // weight [1, 128]
    const int*   src = (const int*)d_in[3];     // src [E]
    const int*   dst = (const int*)d_in[4];     // dst [E]
    float* out = (float*)d_out;

    const int ND = in_sizes[0];          // N * 128
    const int N  = ND / DFEAT;           // 50000
    const int E  = in_sizes[2];          // 800000

    const int EB = (E + EPB - 1) / EPB;             // hist/scatter chunks (196)
    const int NR = (N + RSZ - 1) >> RSH;            // ranges (782)
    const int M  = NR * EB;                         // ghist entries (153272)

    size_t emb_bytes   = ((size_t)ND * sizeof(__half) + 15) & ~(size_t)15;   // 12.8 MB
    size_t ghist_bytes = ((size_t)M * sizeof(u32) + 15) & ~(size_t)15;       // ~0.6 MB
    size_t tsum_bytes  = ((size_t)NB * sizeof(u32) + 15) & ~(size_t)15;      // 2 KB
    size_t pairs_bytes = ((size_t)E * sizeof(u32) + 15) & ~(size_t)15;       // 3.2 MB
    size_t bar_bytes   = 64;
    size_t total_new = emb_bytes + ghist_bytes + tsum_bytes + pairs_bytes + bar_bytes;

    size_t head64_bytes = ((size_t)N * sizeof(u64) + 15) & ~(size_t)15;
    size_t nxt64_bytes  = ((size_t)E * sizeof(u64) + 15) & ~(size_t)15;
    size_t total_old = emb_bytes + head64_bytes + nxt64_bytes;

    int total4 = ND / 4;

    if (ws_size >= total_new && N <= 65536 && NR <= MAXNR && M <= NB * TILE) {
        char* p = (char*)d_ws;
        __half* emb2  = (__half*)p;  p += emb_bytes;
        u32*    ghist = (u32*)p;     p += ghist_bytes;
        u32*    tsum  = (u32*)p;     p += tsum_bytes;
        u32*    pairs = (u32*)p;     p += pairs_bytes;
        u32*    bar   = (u32*)p;     // [0]=barrier counter, [1]=work counter

        hipMemsetAsync(bar, 0, bar_bytes, stream);

        mono_kernel<<<NB, NT, 0, stream>>>(
            x, w, src, dst, emb2, ghist, tsum, pairs, bar, out,
            total4, E, N, EB, NR, M);
    } else if (ws_size >= total_old) {
        char* p = (char*)d_ws;
        __half* emb2 = (__half*)p;  p += emb_bytes;
        u64*    head = (u64*)p;     p += head64_bytes;
        u64*    nxt  = (u64*)p;

        hipMemsetAsync(head, 0xFF, (size_t)N * sizeof(u64), stream);

        int eluBlocks256 = (total4 + 255) / 256;
        int binBlocks = (E + 1023) / 1024;
        bin_elu_ll_kernel<<<binBlocks + eluBlocks256, 256, 0, stream>>>(
            x, w, emb2, total4, src, dst, E, head, nxt, binBlocks);

        long long waves = (N + 1) / 2;
        long long thr = waves * 64;
        gather_ll_kernel<<<(int)((thr + 255) / 256), 256, 0, stream>>>(
            emb2, head, nxt, out, N);
    } else {
        hipMemsetAsync(d_out, 0, (size_t)out_size * sizeof(float), stream);
        long long threads = (long long)E * 32;
        scatter_fused_kernel<<<(int)((threads + 255) / 256), 256, 0, stream>>>(x, w, src, dst, out, E);
    }
}

// Round 5
// 324.585 us; speedup vs baseline: 3.1914x; 1.0115x over previous
//
#include <hip/hip_runtime.h>
#include <hip/hip_fp16.h>
#include <math.h>

#define DFEAT 128
#define RSH 6            // log2(rows per range)
#define RSZ 64           // rows per range
#define NT  512          // threads per block
#define NB  512          // blocks in persistent grid (2 per CU, co-resident)
#define EPB 16384        // edges per hist/scatter chunk
#define EPQ (EPB / NT)   // 32 edges per thread per chunk
#define CHUNK 2048       // pairs per sort chunk in gather
#define MAXNR 1024
#define TILESH 9         // scan tile = 512 elements (== NT)
#define TILE (1 << TILESH)
typedef unsigned long long u64;
typedef unsigned int u32;
typedef unsigned short u16;
#define ENDK 0xFFFFFFFFFFFFFFFFULL

__device__ __forceinline__ void grid_barrier(u32* bar, u32 target) {
    __syncthreads();
    if (threadIdx.x == 0) {
        __threadfence();
        atomicAdd(bar, 1u);
        while (__hip_atomic_load(bar, __ATOMIC_RELAXED, __HIP_MEMORY_SCOPE_AGENT) < target)
            __builtin_amdgcn_s_sleep(8);
        __threadfence();
    }
    __syncthreads();
}

__device__ __forceinline__ void elu_store(const float* x, const float* w,
                                          __half* emb2, int i) {
    float4 xv = ((const float4*)x)[i];
    float4 wv = ((const float4*)w)[i & (DFEAT / 4 - 1)];
    float a, r0, r1, r2, r3;
    a = xv.x * wv.x; r0 = 2.0f * (a > 0.0f ? a : (__expf(a) - 1.0f));
    a = xv.y * wv.y; r1 = 2.0f * (a > 0.0f ? a : (__expf(a) - 1.0f));
    a = xv.z * wv.z; r2 = 2.0f * (a > 0.0f ? a : (__expf(a) - 1.0f));
    a = xv.w * wv.w; r3 = 2.0f * (a > 0.0f ? a : (__expf(a) - 1.0f));
    __half2 h01 = __floats2half2_rn(r0, r1);
    __half2 h23 = __floats2half2_rn(r2, r3);
    uint2 pk;
    pk.x = *(u32*)&h01;
    pk.y = *(u32*)&h23;
    ((uint2*)emb2)[i] = pk;
}

__global__ __launch_bounds__(NT, 4) void mono_kernel(
        const float* __restrict__ x, const float* __restrict__ w,
        const int* __restrict__ src, const int* __restrict__ dst,
        __half* __restrict__ emb2, u32* __restrict__ ghist,
        u32* __restrict__ tsum, u32* __restrict__ pairs,
        u32* __restrict__ bar, float* __restrict__ out,
        int total4, int E, int N, int EB, int NR, int M) {
    __shared__ __align__(16) char shraw[5248];
    __shared__ u32 cur_r;
    const int b = blockIdx.x;
    const int tid = threadIdx.x;
    u32* wrk = bar + 1;

    // ---- P1: per-chunk LDS histogram of dst>>RSH (+ elu grid-strided) ----
    {
        u32* hist = (u32*)shraw;
        for (int c = b; c < EB; c += NB) {
            for (int i = tid; i < NR; i += NT) hist[i] = 0;
            __syncthreads();
            int base = c * EPB;
            for (int q = 0; q < EPQ; ++q) {
                int e = base + tid + q * NT;
                if (e < E) atomicAdd(&hist[((u32)dst[e]) >> RSH], 1u);
            }
            __syncthreads();
            for (int r = tid; r < NR; r += NT)
                ghist[(size_t)r * EB + c] = hist[r];
            __syncthreads();
        }
        for (int i = b * NT + tid; i < total4; i += NB * NT)
            elu_store(x, w, emb2, i);
    }
    grid_barrier(bar, NB);

    // ---- P2a: per-block tile scan (tile = 512, coalesced) ----
    {
        u32* sc = (u32*)shraw;
        int i = (b << TILESH) + tid;
        u32 v = (i < M) ? ghist[i] : 0u;
        sc[tid] = v;
        __syncthreads();
        for (int d = 1; d < NT; d <<= 1) {
            u32 o = (tid >= d) ? sc[tid - d] : 0u;
            __syncthreads();
            sc[tid] += o;
            __syncthreads();
        }
        u32 incl = sc[tid];
        u32 tot = sc[NT - 1];
        if (i < M) ghist[i] = incl - v;       // local-exclusive
        if (tid == 0) tsum[b] = tot;
    }
    grid_barrier(bar, 2 * NB);

    // ---- P2b: block 0 scans the NB tile sums (exclusive) ----
    if (b == 0) {
        u32* sc = (u32*)shraw;
        u32 v = tsum[tid];
        sc[tid] = v;
        __syncthreads();
        for (int d = 1; d < NT; d <<= 1) {
            u32 o = (tid >= d) ? sc[tid - d] : 0u;
            __syncthreads();
            sc[tid] += o;
            __syncthreads();
        }
        tsum[tid] = sc[tid] - v;
    }
    grid_barrier(bar, 3 * NB);

    // ---- P3: scatter pairs into per-(range,chunk) contiguous runs ----
    {
        u32* off = (u32*)shraw;
        for (int c = b; c < EB; c += NB) {
            for (int r = tid; r < NR; r += NT) {
                u32 idx = (u32)r * EB + (u32)c;
                off[r] = ghist[idx] + tsum[idx >> TILESH];
            }
            __syncthreads();
            int base = c * EPB;
            for (int q = 0; q < EPQ; ++q) {
                int e = base + tid + q * NT;
                if (e < E) {
                    u32 d = (u32)dst[e];
                    u32 s = (u32)src[e];
                    u32 p = atomicAdd(&off[d >> RSH], 1u);
                    pairs[p] = ((d & (RSZ - 1)) << 16) | s;
                }
            }
            __syncthreads();
        }
    }
    grid_barrier(bar, 4 * NB);

    // ---- P4: per-range LDS counting-sort by row; scalar-acc gather ----
    // No register arrays anywhere (scratch-spill fix): named scalars only,
    // cross-chunk carry through out[] (this block exclusively owns the range).
    {
        u16* sorted = (u16*)shraw;                       // 4096 B
        u32* bcnt   = (u32*)(shraw + 2 * CHUNK);         // 65 * 4
        u32* bstart = (u32*)(shraw + 2 * CHUNK + 272);   // 65 * 4
        const int wv = tid >> 6;
        const int lane = tid & 63;
        while (true) {
            if (tid == 0) cur_r = atomicAdd(wrk, 1u);
            __syncthreads();
            int r = (int)cur_r;
            if (r >= NR) break;
            u32 ia = (u32)r * (u32)EB;
            u32 s0 = ghist[ia] + tsum[ia >> TILESH];
            u32 ib = ia + (u32)EB;
            u32 s1 = (r + 1 < NR) ? (ghist[ib] + tsum[ib >> TILESH]) : (u32)E;
            u32 pos = s0;
            do {
                int csz = 0;
                if (s1 > pos) {
                    u32 rem = s1 - pos;
                    csz = rem < (u32)CHUNK ? (int)rem : CHUNK;
                }
                if (tid < RSZ + 1) bcnt[tid] = 0;
                __syncthreads();
                u32 p0 = 0, p1 = 0, p2 = 0, p3 = 0;
                int  r0 = -1, r1 = -1, r2 = -1, r3 = -1;
                {
                    int e0 = tid, e1 = tid + NT, e2 = tid + 2 * NT, e3 = tid + 3 * NT;
                    if (e0 < csz) { p0 = pairs[pos + e0]; r0 = (int)(p0 >> 16); }
                    if (e1 < csz) { p1 = pairs[pos + e1]; r1 = (int)(p1 >> 16); }
                    if (e2 < csz) { p2 = pairs[pos + e2]; r2 = (int)(p2 >> 16); }
                    if (e3 < csz) { p3 = pairs[pos + e3]; r3 = (int)(p3 >> 16); }
                    if (r0 >= 0) atomicAdd(&bcnt[r0], 1u);
                    if (r1 >= 0) atomicAdd(&bcnt[r1], 1u);
                    if (r2 >= 0) atomicAdd(&bcnt[r2], 1u);
                    if (r3 >= 0) atomicAdd(&bcnt[r3], 1u);
                }
                __syncthreads();
                if (tid < RSZ) {
                    u32 vv = bcnt[tid];
                    u32 inc = vv;
                    for (int d = 1; d < RSZ; d <<= 1) {
                        u32 o = __shfl_up(inc, d);
                        if (lane >= d) inc += o;
                    }
                    bstart[tid] = inc - vv;
                    bcnt[tid]   = inc - vv;
                    if (tid == RSZ - 1) bstart[RSZ] = inc;
                }
                __syncthreads();
                if (r0 >= 0) { u32 p = atomicAdd(&bcnt[r0], 1u); sorted[p] = (u16)(p0 & 0xFFFFu); }
                if (r1 >= 0) { u32 p = atomicAdd(&bcnt[r1], 1u); sorted[p] = (u16)(p1 & 0xFFFFu); }
                if (r2 >= 0) { u32 p = atomicAdd(&bcnt[r2], 1u); sorted[p] = (u16)(p2 & 0xFFFFu); }
                if (r3 >= 0) { u32 p = atomicAdd(&bcnt[r3], 1u); sorted[p] = (u16)(p3 & 0xFFFFu); }
                __syncthreads();
                // wave wv owns rows [wv*8, wv*8+8); scalar accumulators,
                // 8 unconditional clamped loads per batch (one BB -> 8 in flight)
                for (int rr = 0; rr < 8; ++rr) {
                    int row = (wv << 3) + rr;
                    int n = (r << RSH) + row;
                    int jb = (int)bstart[row], je = (int)bstart[row + 1];
                    float ax, ay;
                    if (pos != s0 && n < N) {
                        float2 t = ((const float2*)out)[(size_t)n * (DFEAT / 2) + lane];
                        ax = t.x; ay = t.y;
                    } else {
                        ax = 0.0f; ay = 0.0f;
                    }
                    for (int j = jb; j < je; j += 8) {
                        int last = je - 1;
                        int j1 = j + 1 < last ? j + 1 : last;
                        int j2 = j + 2 < last ? j + 2 : last;
                        int j3 = j + 3 < last ? j + 3 : last;
                        int j4 = j + 4 < last ? j + 4 : last;
                        int j5 = j + 5 < last ? j + 5 : last;
                        int j6 = j + 6 < last ? j + 6 : last;
                        int j7 = j + 7 < last ? j + 7 : last;
                        u32 q0 = (u32)sorted[j];
                        u32 q1 = (u32)sorted[j1];
                        u32 q2 = (u32)sorted[j2];
                        u32 q3 = (u32)sorted[j3];
                        u32 q4 = (u32)sorted[j4];
                        u32 q5 = (u32)sorted[j5];
                        u32 q6 = (u32)sorted[j6];
                        u32 q7 = (u32)sorted[j7];
                        u32 h0 = ((const u32*)(emb2 + (size_t)q0 * DFEAT))[lane];
                        u32 h1 = ((const u32*)(emb2 + (size_t)q1 * DFEAT))[lane];
                        u32 h2 = ((const u32*)(emb2 + (size_t)q2 * DFEAT))[lane];
                        u32 h3 = ((const u32*)(emb2 + (size_t)q3 * DFEAT))[lane];
                        u32 h4 = ((const u32*)(emb2 + (size_t)q4 * DFEAT))[lane];
                        u32 h5 = ((const u32*)(emb2 + (size_t)q5 * DFEAT))[lane];
                        u32 h6 = ((const u32*)(emb2 + (size_t)q6 * DFEAT))[lane];
                        u32 h7 = ((const u32*)(emb2 + (size_t)q7 * DFEAT))[lane];
                        float2 f0 = __half22float2(*(__half2*)&h0);
                        ax += f0.x; ay += f0.y;
                        if (j + 1 < je) { float2 f = __half22float2(*(__half2*)&h1); ax += f.x; ay += f.y; }
                        if (j + 2 < je) { float2 f = __half22float2(*(__half2*)&h2); ax += f.x; ay += f.y; }
                        if (j + 3 < je) { float2 f = __half22float2(*(__half2*)&h3); ax += f.x; ay += f.y; }
                        if (j + 4 < je) { float2 f = __half22float2(*(__half2*)&h4); ax += f.x; ay += f.y; }
                        if (j + 5 < je) { float2 f = __half22float2(*(__half2*)&h5); ax += f.x; ay += f.y; }
                        if (j + 6 < je) { float2 f = __half22float2(*(__half2*)&h6); ax += f.x; ay += f.y; }
                        if (j + 7 < je) { float2 f = __half22float2(*(__half2*)&h7); ax += f.x; ay += f.y; }
                    }
                    if (n < N)
                        ((float2*)out)[(size_t)n * (DFEAT / 2) + lane] = make_float2(ax, ay);
                }
                __syncthreads();
                pos += CHUNK;
            } while (pos < s1);
        }
    }
}

// ---------------- fallback paths (unchanged) ----------------

__global__ void bin_elu_ll_kernel(const float* __restrict__ x,
                                  const float* __restrict__ w,
                                  __half* __restrict__ emb2, int total4,
                                  const int* __restrict__ src,
                                  const int* __restrict__ dst, int E,
                                  u64* __restrict__ head,
                                  u64* __restrict__ nxt,
                                  int binBlocks) {
    if ((int)blockIdx.x < binBlocks) {
        int base = blockIdx.x * 1024 + threadIdx.x;
        for (int q = 0; q < 4; ++q) {
            int e = base + q * 256;
            if (e < E) {
                int s = src[e];
                int d = dst[e];
                u64 old = atomicExch(&head[d], ((u64)(u32)s << 32) | (u32)e);
                nxt[e] = old;
            }
        }
    } else {
        int idx = (blockIdx.x - binBlocks) * blockDim.x + threadIdx.x;
        if (idx >= total4) return;
        elu_store(x, w, emb2, idx);
    }
}

__global__ void gather_ll_kernel(const __half* __restrict__ emb2,
                                 const u64* __restrict__ head,
                                 const u64* __restrict__ nxt,
                                 float* __restrict__ out, int N) {
    int wid = (blockIdx.x * blockDim.x + threadIdx.x) >> 6;
    int lane = threadIdx.x & 63;
    int nA = wid * 2;
    int nB = nA + 1;
    if (nA >= N) return;
    bool hasB = (nB < N);
    u64 curA = head[nA];
    u64 curB = hasB ? head[nB] : ENDK;
    float2 accA = make_float2(0.0f, 0.0f);
    float2 accB = make_float2(0.0f, 0.0f);
    while (curA != ENDK || curB != ENDK) {
        bool aA = (curA != ENDK);
        bool aB = (curB != ENDK);
        u64 cA = curA, cB = curB;
        u32 uA = 0, uB = 0;
        if (aA) uA = ((const u32*)(emb2 + ((size_t)(cA >> 32)) * DFEAT))[lane];
        if (aB) uB = ((const u32*)(emb2 + ((size_t)(cB >> 32)) * DFEAT))[lane];
        if (aA) curA = nxt[(u32)cA];
        if (aB) curB = nxt[(u32)cB];
        if (aA) {
            float2 f = __half22float2(*(__half2*)&uA);
            accA.x += f.x; accA.y += f.y;
        }
        if (aB) {
            float2 f = __half22float2(*(__half2*)&uB);
            accB.x += f.x; accB.y += f.y;
        }
    }
    ((float2*)(out + (size_t)nA * DFEAT))[lane] = accA;
    if (hasB) ((float2*)(out + (size_t)nB * DFEAT))[lane] = accB;
}

__global__ void scatter_fused_kernel(const float* __restrict__ x,
                                     const float* __restrict__ w,
                                     const int* __restrict__ src,
                                     const int* __restrict__ dst,
                                     float* __restrict__ out, int E) {
    int t = blockIdx.x * blockDim.x + threadIdx.x;
    int edge = t >> 5;
    int lane = t & 31;
    if (edge >= E) return;
    int s = src[edge];
    int d = dst[edge];
    float4 xv = ((const float4*)(x + (size_t)s * DFEAT))[lane];
    float4 wv = ((const float4*)w)[lane];
    float4 v;
    float a;
    a = xv.x * wv.x; v.x = 2.0f * (a > 0.0f ? a : (__expf(a) - 1.0f));
    a = xv.y * wv.y; v.y = 2.0f * (a > 0.0f ? a : (__expf(a) - 1.0f));
    a = xv.z * wv.z; v.z = 2.0f * (a > 0.0f ? a : (__expf(a) - 1.0f));
    a = xv.w * wv.w; v.w = 2.0f * (a > 0.0f ? a : (__expf(a) - 1.0f));
    float* op = out + (size_t)d * DFEAT + lane * 4;
    unsafeAtomicAdd(op + 0, v.x);
    unsafeAtomicAdd(op + 1, v.y);
    unsafeAtomicAdd(op + 2, v.z);
    unsafeAtomicAdd(op + 3, v.w);
}

extern "C" void kernel_launch(void* const* d_in, const int* in_sizes, int n_in,
                              void* d_out, int out_size, void* d_ws, size_t ws_size,
                              hipStream_t stream) {
    const float* x   = (const float*)d_in[0];   // graph_embedding [N, 128]
    const float* w   = (const float*)d_in[1];   // weight [1, 128]
    const int*   src = (const int*)d_in[3];     // src [E]
    const int*   dst = (const int*)d_in[4];     // dst [E]
    float* out = (float*)d_out;

    const int ND = in_sizes[0];          // N * 128
    const int N  = ND / DFEAT;           // 50000
    const int E  = in_sizes[2];          // 800000

    const int EB = (E + EPB - 1) / EPB;             // hist/scatter chunks (49)
    const int NR = (N + RSZ - 1) >> RSH;            // ranges (782)
    const int M  = NR * EB;                         // ghist entries (~38K)

    size_t emb_bytes   = ((size_t)ND * sizeof(__half) + 15) & ~(size_t)15;   // 12.8 MB
    size_t ghist_bytes = ((size_t)M * sizeof(u32) + 15) & ~(size_t)15;       // ~150 KB
    size_t tsum_bytes  = ((size_t)NB * sizeof(u32) + 15) & ~(size_t)15;      // 2 KB
    size_t pairs_bytes = ((size_t)E * sizeof(u32) + 15) & ~(size_t)15;       // 3.2 MB
    size_t bar_bytes   = 64;
    size_t total_new = emb_bytes + ghist_bytes + tsum_bytes + pairs_bytes + bar_bytes;

    size_t head64_bytes = ((size_t)N * sizeof(u64) + 15) & ~(size_t)15;
    size_t nxt64_bytes  = ((size_t)E * sizeof(u64) + 15) & ~(size_t)15;
    size_t total_old = emb_bytes + head64_bytes + nxt64_bytes;

    int total4 = ND / 4;

    if (ws_size >= total_new && N <= 65536 && NR <= MAXNR && M <= NB * TILE) {
        char* p = (char*)d_ws;
        __half* emb2  = (__half*)p;  p += emb_bytes;
        u32*    ghist = (u32*)p;     p += ghist_bytes;
        u32*    tsum  = (u32*)p;     p += tsum_bytes;
        u32*    pairs = (u32*)p;     p += pairs_bytes;
        u32*    bar   = (u32*)p;     // [0]=barrier counter, [1]=work counter

        hipMemsetAsync(bar, 0, bar_bytes, stream);

        mono_kernel<<<NB, NT, 0, stream>>>(
            x, w, src, dst, emb2, ghist, tsum, pairs, bar, out,
            total4, E, N, EB, NR, M);
    } else if (ws_size >= total_old) {
        char* p = (char*)d_ws;
        __half* emb2 = (__half*)p;  p += emb_bytes;
        u64*    head = (u64*)p;     p += head64_bytes;
        u64*    nxt  = (u64*)p;

        hipMemsetAsync(head, 0xFF, (size_t)N * sizeof(u64), stream);

        int eluBlocks256 = (total4 + 255) / 256;
        int binBlocks = (E + 1023) / 1024;
        bin_elu_ll_kernel<<<binBlocks + eluBlocks256, 256, 0, stream>>>(
            x, w, emb2, total4, src, dst, E, head, nxt, binBlocks);

        long long waves = (N + 1) / 2;
        long long thr = waves * 64;
        gather_ll_kernel<<<(int)((thr + 255) / 256), 256, 0, stream>>>(
            emb2, head, nxt, out, N);
    } else {
        hipMemsetAsync(d_out, 0, (size_t)out_size * sizeof(float), stream);
        long long threads = (long long)E * 32;
        scatter_fused_kernel<<<(int)((threads + 255) / 256), 256, 0, stream>>>(x, w, src, dst, out, E);
    }
}

// Round 7
// 138.854 us; speedup vs baseline: 7.4603x; 2.3376x over previous
//
#include <hip/hip_runtime.h>
#include <hip/hip_fp16.h>
#include <math.h>

#define DFEAT 128
#define RSH 6            // log2(rows per range)
#define RSZ 64           // rows per range
#define NT  512          // threads per block
#define EPB 4096         // edges per hist/scatter block
#define EPQ (EPB / NT)   // 8 edges per thread
#define CHUNK 2048       // pairs per sort chunk in gather
#define MAXNR 1024
#define TILESH 9         // scan tile = 512 elements
#define TILE (1 << TILESH)
typedef unsigned long long u64;
typedef unsigned int u32;
typedef unsigned short u16;
#define ENDK 0xFFFFFFFFFFFFFFFFULL

__device__ __forceinline__ void elu_store(const float* x, const float* w,
                                          __half* emb2, int i) {
    float4 xv = ((const float4*)x)[i];
    float4 wv = ((const float4*)w)[i & (DFEAT / 4 - 1)];
    float a, r0, r1, r2, r3;
    a = xv.x * wv.x; r0 = 2.0f * (a > 0.0f ? a : (__expf(a) - 1.0f));
    a = xv.y * wv.y; r1 = 2.0f * (a > 0.0f ? a : (__expf(a) - 1.0f));
    a = xv.z * wv.z; r2 = 2.0f * (a > 0.0f ? a : (__expf(a) - 1.0f));
    a = xv.w * wv.w; r3 = 2.0f * (a > 0.0f ? a : (__expf(a) - 1.0f));
    __half2 h01 = __floats2half2_rn(r0, r1);
    __half2 h23 = __floats2half2_rn(r2, r3);
    uint2 pk;
    pk.x = *(u32*)&h01;
    pk.y = *(u32*)&h23;
    ((uint2*)emb2)[i] = pk;
}

// Redundant per-block exclusive scan of tsum[0..nT) into ts[512] (LDS).
// nT <= 512. Cheap (~10 LDS ops) vs an extra kernel launch.
__device__ __forceinline__ void scan_tsum_lds(const u32* tsum, u32* ts, int nT) {
    int tid = threadIdx.x;
    u32 v = (tid < nT) ? tsum[tid] : 0u;
    ts[tid] = v;
    __syncthreads();
    for (int d = 1; d < NT; d <<= 1) {
        u32 o = (tid >= d) ? ts[tid - d] : 0u;
        __syncthreads();
        ts[tid] += o;
        __syncthreads();
    }
    u32 incl = ts[tid];
    __syncthreads();
    ts[tid] = incl - v;          // exclusive
    __syncthreads();
}

// K1: blocks [0,EB): LDS histogram of dst>>RSH -> ghist[r][block].
//     blocks [EB,..): elu -> emb2 fp16.
__global__ __launch_bounds__(NT) void hist_elu_kernel(
        const float* __restrict__ x, const float* __restrict__ w,
        __half* __restrict__ emb2, int total4,
        const int* __restrict__ dst, int E,
        u32* __restrict__ ghist, int EB, int NR) {
    if ((int)blockIdx.x < EB) {
        __shared__ u32 hist[MAXNR];
        int tid = threadIdx.x;
        for (int i = tid; i < NR; i += NT) hist[i] = 0;
        __syncthreads();
        int base = blockIdx.x * EPB;
        for (int q = 0; q < EPQ; ++q) {
            int e = base + tid + q * NT;
            if (e < E) atomicAdd(&hist[(((u32)dst[e]) >> RSH) & (MAXNR - 1)], 1u);
        }
        __syncthreads();
        for (int r = tid; r < NR; r += NT)
            ghist[(size_t)r * EB + blockIdx.x] = hist[r];
    } else {
        int idx = (blockIdx.x - EB) * NT + threadIdx.x;
        if (idx < total4) elu_store(x, w, emb2, idx);
    }
}

// K2: per-tile local-exclusive scan; tsum[tile] = tile total.
__global__ __launch_bounds__(NT) void scan_tile_kernel(
        u32* __restrict__ g, u32* __restrict__ tsum, int M) {
    __shared__ u32 sc[NT];
    int tid = threadIdx.x;
    int i = (blockIdx.x << TILESH) + tid;
    u32 v = (i < M) ? g[i] : 0u;
    sc[tid] = v;
    __syncthreads();
    for (int d = 1; d < NT; d <<= 1) {
        u32 o = (tid >= d) ? sc[tid - d] : 0u;
        __syncthreads();
        sc[tid] += o;
        __syncthreads();
    }
    if (i < M) g[i] = sc[tid] - v;
    if (tid == NT - 1) tsum[blockIdx.x] = sc[NT - 1];
}

// K3: scatter pairs into per-(range,block) contiguous runs; LDS atomics only.
// pairs[] store bounds-guarded: a logic error can drop edges but never
// write OOB (container-wedge armor).
__global__ __launch_bounds__(NT) void scatter_pairs_kernel(
        const int* __restrict__ src, const int* __restrict__ dst, int E,
        const u32* __restrict__ ghist, const u32* __restrict__ tsum,
        int EB, int NR, int nT, u32* __restrict__ pairs) {
    __shared__ u32 ts[NT];
    __shared__ u32 off[MAXNR];
    int tid = threadIdx.x;
    scan_tsum_lds(tsum, ts, nT);
    for (int r = tid; r < NR; r += NT) {
        u32 idx = (u32)r * EB + blockIdx.x;
        off[r] = ghist[idx] + ts[idx >> TILESH];
    }
    __syncthreads();
    int base = blockIdx.x * EPB;
    for (int q = 0; q < EPQ; ++q) {
        int e = base + tid + q * NT;
        if (e < E) {
            u32 d = (u32)dst[e];
            u32 s = (u32)src[e];
            u32 p = atomicAdd(&off[(d >> RSH) & (MAXNR - 1)], 1u);
            if (p < (u32)E) pairs[p] = ((d & (RSZ - 1)) << 16) | s;
        }
    }
}

// K4: one block per range. LDS counting-sort by local row, then row gather
// with scalar accumulators and 8 clamped loads per batch. No occupancy cap:
// compiler free to use VGPRs for 8-deep MLP. s0/s1 clamped (termination +
// bounds armor).
__global__ __launch_bounds__(NT) void gather_sort_kernel(
        const __half* __restrict__ emb2, const u32* __restrict__ pairs,
        const u32* __restrict__ ghist, const u32* __restrict__ tsum,
        int EB, int NR, int nT, int E,
        float* __restrict__ out, int N) {
    __shared__ u32 ts[NT];
    __shared__ u16 sorted[CHUNK];
    __shared__ u32 bcnt[RSZ + 1];
    __shared__ u32 bstart[RSZ + 1];
    int tid = threadIdx.x;
    scan_tsum_lds(tsum, ts, nT);
    int r = blockIdx.x;
    u32 ia = (u32)r * (u32)EB;
    u32 s0 = ghist[ia] + ts[ia >> TILESH];
    u32 s1 = (r + 1 < NR) ? (ghist[ia + EB] + ts[(ia + EB) >> TILESH]) : (u32)E;
    if (s0 > (u32)E) s0 = (u32)E;
    if (s1 > (u32)E) s1 = (u32)E;
    if (s1 < s0) s1 = s0;
    __syncthreads();   // ts reads done before any reuse patterns
    const int wv = tid >> 6;
    const int lane = tid & 63;
    u32 pos = s0;
    do {
        int csz = 0;
        if (s1 > pos) {
            u32 rem = s1 - pos;
            csz = rem < (u32)CHUNK ? (int)rem : CHUNK;
        }
        if (tid < RSZ + 1) bcnt[tid] = 0;
        __syncthreads();
        u32 p0 = 0, p1 = 0, p2 = 0, p3 = 0;
        int  r0 = -1, r1 = -1, r2 = -1, r3 = -1;
        {
            int e0 = tid, e1 = tid + NT, e2 = tid + 2 * NT, e3 = tid + 3 * NT;
            if (e0 < csz) { p0 = pairs[pos + e0]; r0 = (int)(p0 >> 16); }
            if (e1 < csz) { p1 = pairs[pos + e1]; r1 = (int)(p1 >> 16); }
            if (e2 < csz) { p2 = pairs[pos + e2]; r2 = (int)(p2 >> 16); }
            if (e3 < csz) { p3 = pairs[pos + e3]; r3 = (int)(p3 >> 16); }
            if (r0 >= 0) atomicAdd(&bcnt[r0 & (RSZ - 1)], 1u);
            if (r1 >= 0) atomicAdd(&bcnt[r1 & (RSZ - 1)], 1u);
            if (r2 >= 0) atomicAdd(&bcnt[r2 & (RSZ - 1)], 1u);
            if (r3 >= 0) atomicAdd(&bcnt[r3 & (RSZ - 1)], 1u);
        }
        __syncthreads();
        if (tid < RSZ) {
            u32 vv = bcnt[tid];
            u32 inc = vv;
            for (int d = 1; d < RSZ; d <<= 1) {
                u32 o = __shfl_up(inc, d);
                if (lane >= d) inc += o;
            }
            bstart[tid] = inc - vv;
            bcnt[tid]   = inc - vv;
            if (tid == RSZ - 1) bstart[RSZ] = inc;
        }
        __syncthreads();
        if (r0 >= 0) { u32 p = atomicAdd(&bcnt[r0 & (RSZ - 1)], 1u); sorted[p & (CHUNK - 1)] = (u16)(p0 & 0xFFFFu); }
        if (r1 >= 0) { u32 p = atomicAdd(&bcnt[r1 & (RSZ - 1)], 1u); sorted[p & (CHUNK - 1)] = (u16)(p1 & 0xFFFFu); }
        if (r2 >= 0) { u32 p = atomicAdd(&bcnt[r2 & (RSZ - 1)], 1u); sorted[p & (CHUNK - 1)] = (u16)(p2 & 0xFFFFu); }
        if (r3 >= 0) { u32 p = atomicAdd(&bcnt[r3 & (RSZ - 1)], 1u); sorted[p & (CHUNK - 1)] = (u16)(p3 & 0xFFFFu); }
        __syncthreads();
        for (int rr = 0; rr < 8; ++rr) {
            int row = (wv << 3) + rr;
            int n = (r << RSH) + row;
            int jb = (int)bstart[row], je = (int)bstart[row + 1];
            float ax, ay;
            if (pos != s0 && n < N) {
                float2 t = ((const float2*)out)[(size_t)n * (DFEAT / 2) + lane];
                ax = t.x; ay = t.y;
            } else {
                ax = 0.0f; ay = 0.0f;
            }
            for (int j = jb; j < je; j += 8) {
                int last = je - 1;
                int j1 = j + 1 < last ? j + 1 : last;
                int j2 = j + 2 < last ? j + 2 : last;
                int j3 = j + 3 < last ? j + 3 : last;
                int j4 = j + 4 < last ? j + 4 : last;
                int j5 = j + 5 < last ? j + 5 : last;
                int j6 = j + 6 < last ? j + 6 : last;
                int j7 = j + 7 < last ? j + 7 : last;
                u32 q0 = (u32)sorted[j];
                u32 q1 = (u32)sorted[j1];
                u32 q2 = (u32)sorted[j2];
                u32 q3 = (u32)sorted[j3];
                u32 q4 = (u32)sorted[j4];
                u32 q5 = (u32)sorted[j5];
                u32 q6 = (u32)sorted[j6];
                u32 q7 = (u32)sorted[j7];
                u32 h0 = ((const u32*)(emb2 + (size_t)q0 * DFEAT))[lane];
                u32 h1 = ((const u32*)(emb2 + (size_t)q1 * DFEAT))[lane];
                u32 h2 = ((const u32*)(emb2 + (size_t)q2 * DFEAT))[lane];
                u32 h3 = ((const u32*)(emb2 + (size_t)q3 * DFEAT))[lane];
                u32 h4 = ((const u32*)(emb2 + (size_t)q4 * DFEAT))[lane];
                u32 h5 = ((const u32*)(emb2 + (size_t)q5 * DFEAT))[lane];
                u32 h6 = ((const u32*)(emb2 + (size_t)q6 * DFEAT))[lane];
                u32 h7 = ((const u32*)(emb2 + (size_t)q7 * DFEAT))[lane];
                float2 f0 = __half22float2(*(__half2*)&h0);
                ax += f0.x; ay += f0.y;
                if (j + 1 < je) { float2 f = __half22float2(*(__half2*)&h1); ax += f.x; ay += f.y; }
                if (j + 2 < je) { float2 f = __half22float2(*(__half2*)&h2); ax += f.x; ay += f.y; }
                if (j + 3 < je) { float2 f = __half22float2(*(__half2*)&h3); ax += f.x; ay += f.y; }
                if (j + 4 < je) { float2 f = __half22float2(*(__half2*)&h4); ax += f.x; ay += f.y; }
                if (j + 5 < je) { float2 f = __half22float2(*(__half2*)&h5); ax += f.x; ay += f.y; }
                if (j + 6 < je) { float2 f = __half22float2(*(__half2*)&h6); ax += f.x; ay += f.y; }
                if (j + 7 < je) { float2 f = __half22float2(*(__half2*)&h7); ax += f.x; ay += f.y; }
            }
            if (n < N)
                ((float2*)out)[(size_t)n * (DFEAT / 2) + lane] = make_float2(ax, ay);
        }
        __syncthreads();
        pos += CHUNK;
    } while (pos < s1);
}

// ---------------- fallback paths (unchanged) ----------------

__global__ void bin_elu_ll_kernel(const float* __restrict__ x,
                                  const float* __restrict__ w,
                                  __half* __restrict__ emb2, int total4,
                                  const int* __restrict__ src,
                                  const int* __restrict__ dst, int E,
                                  u64* __restrict__ head,
                                  u64* __restrict__ nxt,
                                  int binBlocks) {
    if ((int)blockIdx.x < binBlocks) {
        int base = blockIdx.x * 1024 + threadIdx.x;
        for (int q = 0; q < 4; ++q) {
            int e = base + q * 256;
            if (e < E) {
                int s = src[e];
                int d = dst[e];
                u64 old = atomicExch(&head[d], ((u64)(u32)s << 32) | (u32)e);
                nxt[e] = old;
            }
        }
    } else {
        int idx = (blockIdx.x - binBlocks) * blockDim.x + threadIdx.x;
        if (idx >= total4) return;
        elu_store(x, w, emb2, idx);
    }
}

__global__ void gather_ll_kernel(const __half* __restrict__ emb2,
                                 const u64* __restrict__ head,
                                 const u64* __restrict__ nxt,
                                 float* __restrict__ out, int N) {
    int wid = (blockIdx.x * blockDim.x + threadIdx.x) >> 6;
    int lane = threadIdx.x & 63;
    int nA = wid * 2;
    int nB = nA + 1;
    if (nA >= N) return;
    bool hasB = (nB < N);
    u64 curA = head[nA];
    u64 curB = hasB ? head[nB] : ENDK;
    float2 accA = make_float2(0.0f, 0.0f);
    float2 accB = make_float2(0.0f, 0.0f);
    while (curA != ENDK || curB != ENDK) {
        bool aA = (curA != ENDK);
        bool aB = (curB != ENDK);
        u64 cA = curA, cB = curB;
        u32 uA = 0, uB = 0;
        if (aA) uA = ((const u32*)(emb2 + ((size_t)(cA >> 32)) * DFEAT))[lane];
        if (aB) uB = ((const u32*)(emb2 + ((size_t)(cB >> 32)) * DFEAT))[lane];
        if (aA) curA = nxt[(u32)cA];
        if (aB) curB = nxt[(u32)cB];
        if (aA) {
            float2 f = __half22float2(*(__half2*)&uA);
            accA.x += f.x; accA.y += f.y;
        }
        if (aB) {
            float2 f = __half22float2(*(__half2*)&uB);
            accB.x += f.x; accB.y += f.y;
        }
    }
    ((float2*)(out + (size_t)nA * DFEAT))[lane] = accA;
    if (hasB) ((float2*)(out + (size_t)nB * DFEAT))[lane] = accB;
}

__global__ void scatter_fused_kernel(const float* __restrict__ x,
                                     const float* __restrict__ w,
                                     const int* __restrict__ src,
                                     const int* __restrict__ dst,
                                     float* __restrict__ out, int E) {
    int t = blockIdx.x * blockDim.x + threadIdx.x;
    int edge = t >> 5;
    int lane = t & 31;
    if (edge >= E) return;
    int s = src[edge];
    int d = dst[edge];
    float4 xv = ((const float4*)(x + (size_t)s * DFEAT))[lane];
    float4 wv = ((const float4*)w)[lane];
    float4 v;
    float a;
    a = xv.x * wv.x; v.x = 2.0f * (a > 0.0f ? a : (__expf(a) - 1.0f));
    a = xv.y * wv.y; v.y = 2.0f * (a > 0.0f ? a : (__expf(a) - 1.0f));
    a = xv.z * wv.z; v.z = 2.0f * (a > 0.0f ? a : (__expf(a) - 1.0f));
    a = xv.w * wv.w; v.w = 2.0f * (a > 0.0f ? a : (__expf(a) - 1.0f));
    float* op = out + (size_t)d * DFEAT + lane * 4;
    unsafeAtomicAdd(op + 0, v.x);
    unsafeAtomicAdd(op + 1, v.y);
    unsafeAtomicAdd(op + 2, v.z);
    unsafeAtomicAdd(op + 3, v.w);
}

extern "C" void kernel_launch(void* const* d_in, const int* in_sizes, int n_in,
                              void* d_out, int out_size, void* d_ws, size_t ws_size,
                              hipStream_t stream) {
    const float* x   = (const float*)d_in[0];   // graph_embedding [N, 128]
    const float* w   = (const float*)d_in[1];   // weight [1, 128]
    const int*   src = (const int*)d_in[3];     // src [E]
    const int*   dst = (const int*)d_in[4];     // dst [E]
    float* out = (float*)d_out;

    const int ND = in_sizes[0];          // N * 128
    const int N  = ND / DFEAT;           // 50000
    const int E  = in_sizes[2];          // 800000

    const int EB = (E + EPB - 1) / EPB;             // hist/scatter blocks (196)
    const int NR = (N + RSZ - 1) >> RSH;            // ranges (782)
    const int M  = NR * EB;                         // ghist entries (~153K)
    const int nT = (M + TILE - 1) >> TILESH;        // scan tiles (~300)

    size_t emb_bytes   = ((size_t)ND * sizeof(__half) + 15) & ~(size_t)15;   // 12.8 MB
    size_t ghist_bytes = ((size_t)M * sizeof(u32) + 15) & ~(size_t)15;       // ~0.6 MB
    size_t tsum_bytes  = ((size_t)NT * sizeof(u32) + 15) & ~(size_t)15;      // 2 KB
    size_t pairs_bytes = ((size_t)E * sizeof(u32) + 15) & ~(size_t)15;       // 3.2 MB
    size_t total_new = emb_bytes + ghist_bytes + tsum_bytes + pairs_bytes;

    size_t head64_bytes = ((size_t)N * sizeof(u64) + 15) & ~(size_t)15;
    size_t nxt64_bytes  = ((size_t)E * sizeof(u64) + 15) & ~(size_t)15;
    size_t total_old = emb_bytes + head64_bytes + nxt64_bytes;

    int total4 = ND / 4;

    if (ws_size >= total_new && N <= 65536 && NR <= MAXNR && nT <= NT) {
        char* p = (char*)d_ws;
        __half* emb2  = (__half*)p;  p += emb_bytes;
        u32*    ghist = (u32*)p;     p += ghist_bytes;
        u32*    tsum  = (u32*)p;     p += tsum_bytes;
        u32*    pairs = (u32*)p;

        int eluBlocks = (total4 + NT - 1) / NT;
        hist_elu_kernel<<<EB + eluBlocks, NT, 0, stream>>>(
            x, w, emb2, total4, dst, E, ghist, EB, NR);

        scan_tile_kernel<<<nT, NT, 0, stream>>>(ghist, tsum, M);

        scatter_pairs_kernel<<<EB, NT, 0, stream>>>(
            src, dst, E, ghist, tsum, EB, NR, nT, pairs);

        gather_sort_kernel<<<NR, NT, 0, stream>>>(
            emb2, pairs, ghist, tsum, EB, NR, nT, E, out, N);
    } else if (ws_size >= total_old) {
        char* p = (char*)d_ws;
        __half* emb2 = (__half*)p;  p += emb_bytes;
        u64*    head = (u64*)p;     p += head64_bytes;
        u64*    nxt  = (u64*)p;

        hipMemsetAsync(head, 0xFF, (size_t)N * sizeof(u64), stream);

        int eluBlocks256 = (total4 + 255) / 256;
        int binBlocks = (E + 1023) / 1024;
        bin_elu_ll_kernel<<<binBlocks + eluBlocks256, 256, 0, stream>>>(
            x, w, emb2, total4, src, dst, E, head, nxt, binBlocks);

        long long waves = (N + 1) / 2;
        long long thr = waves * 64;
        gather_ll_kernel<<<(int)((thr + 255) / 256), 256, 0, stream>>>(
            emb2, head, nxt, out, N);
    } else {
        hipMemsetAsync(d_out, 0, (size_t)out_size * sizeof(float), stream);
        long long threads = (long long)E * 32;
        scatter_fused_kernel<<<(int)((threads + 255) / 256), 256, 0, stream>>>(x, w, src, dst, out, E);
    }
}